// Round 3
// baseline (1556.788 us; speedup 1.0000x reference)
//
#include <hip/hip_runtime.h>
#include <hip/hip_bf16.h>
#include <math.h>

typedef __attribute__((ext_vector_type(8))) short short8;   // 8 x bf16 (4 VGPRs)
typedef __attribute__((ext_vector_type(4))) float f32x4;    // MFMA C/D frag

#define NN    21
#define DD    256
#define GH    512
#define NE    40
#define BT    6               // batches per workgroup
#define MROWS (BT * NN)       // 126 real rows
#define MPAD  128             // padded M tile
#define NTHR  512
#define UVSTR 36              // fp32 row stride for uv (32 + 4)

__device__ __forceinline__ f32x4 mfma16(short8 a, short8 b, f32x4 c) {
    return __builtin_amdgcn_mfma_f32_16x16x32_bf16(a, b, c, 0, 0, 0);
}

// ---------------------------------------------------------------------------
// Prep: transpose weights to bf16 [n][k] layouts. WvT[f][d] = Wv[d][f];
// WtT[h][c] = W1[c][h] (c<256); WbT[h][c] = W1[256+c][h].
// ---------------------------------------------------------------------------
__global__ void prep_weights(const float* __restrict__ Wv, const float* __restrict__ W1,
                             __hip_bfloat16* __restrict__ WvT,
                             __hip_bfloat16* __restrict__ WtT,
                             __hip_bfloat16* __restrict__ WbT) {
    __shared__ float tile[64][65];
    int bi = blockIdx.x;
    const float* src;
    int ld, tc, th;
    bool isW1 = bi < 64;
    if (isW1) { src = W1; ld = 512; tc = (bi & 7) * 64; th = (bi >> 3) * 64; }
    else      { int b = bi - 64; src = Wv; ld = 256; tc = (b & 3) * 64; th = (b >> 2) * 64; }
    for (int i = 0; i < 16; ++i) {
        int e = threadIdx.x + 256 * i;
        int r = e >> 6, cc = e & 63;
        tile[r][cc] = src[(size_t)(tc + r) * ld + th + cc];
    }
    __syncthreads();
    for (int i = 0; i < 16; ++i) {
        int e  = threadIdx.x + 256 * i;
        int r2 = e >> 6, cc2 = e & 63;
        float v = tile[cc2][r2];
        int hh = th + r2, c = tc + cc2;
        if (isW1) {
            if (c < 256) WtT[hh * 256 + c]         = __float2bfloat16(v);
            else         WbT[hh * 256 + (c - 256)] = __float2bfloat16(v);
        } else {
            WvT[hh * 256 + c] = __float2bfloat16(v);
        }
    }
}

// ---------------------------------------------------------------------------
// Fused kernel. 1 WG = 6 batches (126 rows, pad 128), 512 threads / 8 waves.
// A-fragments in registers (extracted in two 64-row LDS passes); weight chunks
// prefetched into registers one iteration ahead so L2 latency hides under MFMA.
// XOR swizzle: content 16B-granule g of row r stored at phys granule g^(r&7).
// ---------------------------------------------------------------------------
__launch_bounds__(NTHR, 6)
__global__ void fused_kernel(const float* __restrict__ hin,
                             const int* __restrict__ srci, const int* __restrict__ dsti,
                             const float* __restrict__ lnw, const float* __restrict__ lnb,
                             const float* __restrict__ bv,  const float* __restrict__ b1,
                             const float* __restrict__ W2,  const float* __restrict__ b2,
                             const __hip_bfloat16* __restrict__ WvT,
                             const __hip_bfloat16* __restrict__ WtT,
                             const __hip_bfloat16* __restrict__ WbT,
                             float* __restrict__ out, int Btotal) {
    // phase A (per 64-row half): xs rows 0..63 x 512 B swizzled bf16 (32 KB)
    // phase B: wst = smem[0..16384) (32 rows x 512 B swizzled bf16),
    //          uv  = (float*)(smem+16384), [128][UVSTR] (18 KB)
    __shared__ __align__(16) char smem[16384 + MPAD * UVSTR * 4];
    __shared__ float b1s[GH], w2s[GH], bvs[DD];
    __shared__ float gates[BT * NE];
    __shared__ int   srcs[NE], dsts[NE];
    __shared__ int   csr_off[NN + 1], csr_cur[NN], csr_eid[NE];

    const int tid  = threadIdx.x;
    const int lane = tid & 63;
    const int w    = tid >> 6;          // wave 0..7
    const int b0   = blockIdx.x * BT;

    if (tid < NE) { srcs[tid] = srci[tid]; dsts[tid] = dsti[tid]; }
    b1s[tid] = b1[tid];
    w2s[tid] = W2[tid];
    if (tid < DD) bvs[tid] = bv[tid];
    if (tid <= NN) csr_off[tid] = 0;
    int myd = (tid < NE) ? dsti[tid] : 0;
    __syncthreads();
    if (tid < NE) atomicAdd(&csr_off[myd + 1], 1);

    // wave tile: mq = m-block (32 rows), nsel = U/V (or Val col-half)
    const int mq   = w & 3;
    const int nsel = w >> 2;
    const int l15  = lane & 15;
    const int lq   = lane >> 4;
    short8 afr[2][8];

    // ---- Phase 1: LayerNorm -> xs (two 64-row halves) + A-frag extraction ----
    {
        float4 wgt = ((const float4*)lnw)[lane];
        float4 bta = ((const float4*)lnb)[lane];
        for (int half = 0; half < 2; ++half) {
            float4 hv[8];
            int rbase = half * 64 + w * 8;
            #pragma unroll
            for (int i = 0; i < 8; ++i) {
                int r = rbase + i;
                int b_loc = r / NN;
                int node  = r - b_loc * NN;
                bool valid = (r < MROWS) && (b0 + b_loc < Btotal);
                if (valid)
                    hv[i] = *(const float4*)(hin + ((size_t)(b0 + b_loc) * NN + node) * DD + lane * 4);
                else
                    hv[i] = (float4){0.f, 0.f, 0.f, 0.f};
            }
            #pragma unroll
            for (int i = 0; i < 8; ++i) {
                float4 h4 = hv[i];
                float s  = h4.x + h4.y + h4.z + h4.w;
                float ss = h4.x*h4.x + h4.y*h4.y + h4.z*h4.z + h4.w*h4.w;
                for (int off = 32; off; off >>= 1) {
                    s  += __shfl_xor(s,  off);
                    ss += __shfl_xor(ss, off);
                }
                float mu   = s * (1.0f / 256.0f);
                float rstd = rsqrtf(ss * (1.0f / 256.0f) - mu * mu + 1e-5f);
                __align__(8) __hip_bfloat16 t[4];
                t[0] = __float2bfloat16((h4.x - mu) * rstd * wgt.x + bta.x);
                t[1] = __float2bfloat16((h4.y - mu) * rstd * wgt.y + bta.y);
                t[2] = __float2bfloat16((h4.z - mu) * rstd * wgt.z + bta.z);
                t[3] = __float2bfloat16((h4.w - mu) * rstd * wgt.w + bta.w);
                int pr = w * 8 + i;     // physical row in this half
                char* dst = smem + pr * 512 + ((((lane >> 1) ^ (pr & 7)) << 4) | ((lane & 1) << 3));
                *(ushort4*)dst = *(ushort4*)&t[0];
            }
            __syncthreads();
            if (half == 0 && tid == 0) {   // CSR build once, overlapped
                for (int n = 0; n < NN; ++n) csr_off[n + 1] += csr_off[n];
                for (int n = 0; n < NN; ++n) csr_cur[n] = csr_off[n];
                for (int e = 0; e < NE; ++e) { int d = dsts[e]; csr_eid[csr_cur[d]++] = e; }
            }
            if ((mq >> 1) == half) {       // this wave's m-block lives in this half
                #pragma unroll
                for (int mt = 0; mt < 2; ++mt) {
                    int pr = 32 * (mq & 1) + 16 * mt + l15;
                    const char* rowp = smem + pr * 512;
                    int swz = pr & 7;
                    #pragma unroll
                    for (int ki = 0; ki < 8; ++ki)
                        afr[mt][ki] = *(const short8*)(rowp + ((((ki << 2) + lq) ^ swz) << 4));
                }
            }
            __syncthreads();
        }
    }

    float* uvp = (float*)(smem + 16384);

    // gate ownership: pair p = tid>>1 (BT*NE=240 pairs), j-half = tid&1
    const bool gactive = tid < 2 * BT * NE;   // 480
    int rs = 0, rd = 0;
    if (gactive) {
        int p  = tid >> 1;
        int pb = p / NE, pe = p - pb * NE;
        rs = pb * NN + srcs[pe];
        rd = pb * NN + dsts[pe];
    }
    const int jh = tid & 1;

    // stage U/V chunk 0 directly
    #pragma unroll
    for (int i = 0; i < 2; ++i) {
        int v = tid + NTHR * i;
        int row = v >> 5, pg = v & 31;
        int cg = pg ^ (row & 7);
        const __hip_bfloat16* sp = (row < 16)
            ? (WtT + (size_t)row * 256 + cg * 8)
            : (WbT + (size_t)(row - 16) * 256 + cg * 8);
        *(float4*)(smem + row * 512 + pg * 16) = *(const float4*)sp;
    }
    __syncthreads();

    // ---- Phase 2: 32 chunks of 16 gh-cols (U and V simultaneously) ----
    float gacc = 0.0f;
    const int   brow_r = 16 * nsel + l15;
    const char* browp  = smem + brow_r * 512;
    const int   bswz   = l15 & 7;
    for (int c = 0; c < 32; ++c) {
        float4 wreg[2];
        if (c + 1 < 32) {   // prefetch next weight chunk into registers
            int cb = c + 1;
            #pragma unroll
            for (int i = 0; i < 2; ++i) {
                int v = tid + NTHR * i;
                int row = v >> 5, pg = v & 31;
                int cg = pg ^ (row & 7);
                const __hip_bfloat16* sp = (row < 16)
                    ? (WtT + (size_t)(cb * 16 + row) * 256 + cg * 8)
                    : (WbT + (size_t)(cb * 16 + row - 16) * 256 + cg * 8);
                wreg[i] = *(const float4*)sp;
            }
        }
        f32x4 acc0 = {0.f,0.f,0.f,0.f}, acc1 = {0.f,0.f,0.f,0.f};
        #pragma unroll
        for (int ki = 0; ki < 8; ++ki) {
            short8 bf = *(const short8*)(browp + ((((ki << 2) + lq) ^ bswz) << 4));
            acc0 = mfma16(afr[0][ki], bf, acc0);
            acc1 = mfma16(afr[1][ki], bf, acc1);
        }
        {
            int col = 16 * nsel + l15;
            #pragma unroll
            for (int r = 0; r < 4; ++r) {
                uvp[(32 * mq +      4 * lq + r) * UVSTR + col] = acc0[r];
                uvp[(32 * mq + 16 + 4 * lq + r) * UVSTR + col] = acc1[r];
            }
        }
        __syncthreads();
        if (c + 1 < 32) {   // commit prefetched weights (old wst readers all done)
            #pragma unroll
            for (int i = 0; i < 2; ++i) {
                int v = tid + NTHR * i;
                int row = v >> 5, pg = v & 31;
                *(float4*)(smem + row * 512 + pg * 16) = wreg[i];
            }
        }
        if (gactive) {      // gate partials: gelu(U[src]+V[dst]+b1) . W2
            const float* up  = uvp + rs * UVSTR + jh * 8;
            const float* vp  = uvp + rd * UVSTR + 16 + jh * 8;
            const float* b1p = b1s + c * 16 + jh * 8;
            const float* w2p = w2s + c * 16 + jh * 8;
            #pragma unroll
            for (int jj = 0; jj < 8; ++jj) {
                float z = up[jj] + vp[jj] + b1p[jj];
                float y = 1.5957691216f * (z + 0.044715f * z * z * z);
                float sg = 1.0f / (1.0f + __expf(-y));
                gacc += z * sg * w2p[jj];
            }
        }
        __syncthreads();
    }

    // ---- Phase 3: finalize gates + stage Val chunk 0 ----
    if (gactive) {
        float other = __shfl_xor(gacc, 1);
        if (jh == 0) {
            float tot = gacc + other + b2[0];
            gates[tid >> 1] = 1.0f / (1.0f + __expf(-tot));
        }
    }
    #pragma unroll
    for (int i = 0; i < 2; ++i) {
        int v = tid + NTHR * i;
        int row = v >> 5, pg = v & 31;
        int cg = pg ^ (row & 7);
        *(float4*)(smem + row * 512 + pg * 16) =
            *(const float4*)(WvT + (size_t)row * 256 + cg * 8);
    }
    __syncthreads();

    // per-thread aggregation slots (fixed across vc)
    const int q0 = tid, q1 = tid + NTHR;
    const int row0 = q0 >> 3, g0 = q0 & 7;
    const int row1 = q1 >> 3, g1 = q1 & 7;
    const int bl0 = row0 / NN, nd0 = row0 - bl0 * NN;
    const int bl1 = (q1 < MROWS * 8) ? row1 / NN : 0;
    const int nd1 = row1 - bl1 * NN;
    const bool av0 = (b0 + bl0 < Btotal);
    const bool av1 = (q1 < MROWS * 8) && (b0 + bl1 < Btotal);
    const size_t base0 = ((size_t)(b0 + bl0) * NN + nd0) * DD;
    const size_t base1 = ((size_t)(b0 + bl1) * NN + nd1) * DD;

    // ---- Phase 4: 8 Val chunks (32 f-cols) -> CSR aggregation -> out ----
    for (int vc = 0; vc < 8; ++vc) {
        float4 wreg[2];
        if (vc + 1 < 8) {
            int vb = vc + 1;
            #pragma unroll
            for (int i = 0; i < 2; ++i) {
                int v = tid + NTHR * i;
                int row = v >> 5, pg = v & 31;
                int cg = pg ^ (row & 7);
                wreg[i] = *(const float4*)(WvT + (size_t)(vb * 32 + row) * 256 + cg * 8);
            }
        }
        float4 h0 = {0.f,0.f,0.f,0.f}, h1 = {0.f,0.f,0.f,0.f};
        if (av0) h0 = *(const float4*)(hin + base0 + vc * 32 + g0 * 4);
        if (av1) h1 = *(const float4*)(hin + base1 + vc * 32 + g1 * 4);

        f32x4 acc0 = {0.f,0.f,0.f,0.f}, acc1 = {0.f,0.f,0.f,0.f};
        #pragma unroll
        for (int ki = 0; ki < 8; ++ki) {
            short8 bf = *(const short8*)(browp + ((((ki << 2) + lq) ^ bswz) << 4));
            acc0 = mfma16(afr[0][ki], bf, acc0);
            acc1 = mfma16(afr[1][ki], bf, acc1);
        }
        {
            int col = 16 * nsel + l15;
            float bvv = bvs[vc * 32 + col];
            #pragma unroll
            for (int r = 0; r < 4; ++r) {
                uvp[(32 * mq +      4 * lq + r) * UVSTR + col] = acc0[r] + bvv;
                uvp[(32 * mq + 16 + 4 * lq + r) * UVSTR + col] = acc1[r] + bvv;
            }
        }
        __syncthreads();
        if (vc + 1 < 8) {
            #pragma unroll
            for (int i = 0; i < 2; ++i) {
                int v = tid + NTHR * i;
                int row = v >> 5, pg = v & 31;
                *(float4*)(smem + row * 512 + pg * 16) = wreg[i];
            }
        }
        if (av0) {
            float a0 = h0.x, a1 = h0.y, a2 = h0.z, a3 = h0.w;
            int e1 = csr_off[nd0 + 1];
            for (int ii = csr_off[nd0]; ii < e1; ++ii) {
                int e  = csr_eid[ii];
                float gv = gates[bl0 * NE + e];
                const float* vp = uvp + (bl0 * NN + srcs[e]) * UVSTR + g0 * 4;
                a0 += gv * vp[0]; a1 += gv * vp[1];
                a2 += gv * vp[2]; a3 += gv * vp[3];
            }
            float4 o = {a0, a1, a2, a3};
            *(float4*)(out + base0 + vc * 32 + g0 * 4) = o;
        }
        if (av1) {
            float a0 = h1.x, a1 = h1.y, a2 = h1.z, a3 = h1.w;
            int e1 = csr_off[nd1 + 1];
            for (int ii = csr_off[nd1]; ii < e1; ++ii) {
                int e  = csr_eid[ii];
                float gv = gates[bl1 * NE + e];
                const float* vp = uvp + (bl1 * NN + srcs[e]) * UVSTR + g1 * 4;
                a0 += gv * vp[0]; a1 += gv * vp[1];
                a2 += gv * vp[2]; a3 += gv * vp[3];
            }
            float4 o = {a0, a1, a2, a3};
            *(float4*)(out + base1 + vc * 32 + g1 * 4) = o;
        }
        __syncthreads();
    }
}

extern "C" void kernel_launch(void* const* d_in, const int* in_sizes, int n_in,
                              void* d_out, int out_size, void* d_ws, size_t ws_size,
                              hipStream_t stream) {
    const float* h   = (const float*)d_in[0];
    const int*  srci = (const int*)d_in[1];
    const int*  dsti = (const int*)d_in[2];
    const float* lnw = (const float*)d_in[3];
    const float* lnb = (const float*)d_in[4];
    const float* Wv  = (const float*)d_in[5];
    const float* bv  = (const float*)d_in[6];
    const float* W1  = (const float*)d_in[7];
    const float* b1  = (const float*)d_in[8];
    const float* W2  = (const float*)d_in[9];
    const float* b2  = (const float*)d_in[10];
    float* out = (float*)d_out;

    __hip_bfloat16* WvT = (__hip_bfloat16*)d_ws;       // 256*256
    __hip_bfloat16* WtT = WvT + 256 * 256;             // 512*256
    __hip_bfloat16* WbT = WtT + 512 * 256;             // 512*256

    int Btotal = in_sizes[0] / (NN * DD);
    prep_weights<<<80, 256, 0, stream>>>(Wv, W1, WvT, WtT, WbT);
    int grid = (Btotal + BT - 1) / BT;
    fused_kernel<<<grid, NTHR, 0, stream>>>(h, srci, dsti, lnw, lnb, bv, b1, W2, b2,
                                            WvT, WtT, WbT, out, Btotal);
}